// Round 3
// baseline (1945.188 us; speedup 1.0000x reference)
//
#include <hip/hip_runtime.h>
#include <math.h>

typedef _Float16 f16;
typedef _Float16 f16x4 __attribute__((ext_vector_type(4)));
typedef _Float16 f16x8 __attribute__((ext_vector_type(8)));
typedef float f32x4 __attribute__((ext_vector_type(4)));

#define SEQ   2048
#define DIM   1024
#define NH    16
#define DH    64
#define NCOLS 6144
#define NHSD  (NH*SEQ*DH)   /* 2,097,152 elements per qkv sub-tensor */
#define MAXSPLIT 4
#define SPLITS_PER_HEAD 32  /* sum of S(I) over I=0..15 */

__device__ __forceinline__ int nsplits(int I) {
  return (I < 7) ? 1 : (I < 11) ? 2 : (I < 14) ? 3 : 4;
}

// ---------------- cast x (fp32 -> f16), vectorized x4 ----------------
__global__ __launch_bounds__(256) void k_cast_x(const float* __restrict__ x, f16* __restrict__ xh) {
  int i = (blockIdx.x * 256 + threadIdx.x) * 4;
  float4 v = *(const float4*)(x + i);
  f16x4 h; h[0] = (f16)v.x; h[1] = (f16)v.y; h[2] = (f16)v.z; h[3] = (f16)v.w;
  *(f16x4*)(xh + i) = h;
}

// ------------- transpose + cast: out[c][r] = (f16) in[r][c], in is R x C -------------
__global__ __launch_bounds__(256) void k_tcast(const float* __restrict__ in, f16* __restrict__ out,
                                               int R, int C) {
  __shared__ f16 t[64 * 66];
  int bc = blockIdx.x, br = blockIdx.y;
  for (int it = 0; it < 16; ++it) {
    int idx = it * 256 + threadIdx.x;
    int r = idx >> 6, c = idx & 63;
    t[r * 66 + c] = (f16)in[(size_t)(br * 64 + r) * C + bc * 64 + c];
  }
  __syncthreads();
  for (int it = 0; it < 16; ++it) {
    int idx = it * 256 + threadIdx.x;
    int oc = idx >> 6, orr = idx & 63;
    out[(size_t)(bc * 64 + oc) * R + br * 64 + orr] = t[orr * 66 + oc];
  }
}

// ---------------- qkv GEMM: xh[2048,1024] @ WqT[6144,1024]^T -> six packed tensors ----------------
__global__ __launch_bounds__(256) void k_gemm_qkv(const f16* __restrict__ A, const f16* __restrict__ B,
                                                  f16* __restrict__ q6) {
  __shared__ f16 sa[128 * 72];
  __shared__ f16 sb[128 * 72];
  int bx = blockIdx.x, by = blockIdx.y;
  int tid = threadIdx.x, w = tid >> 6, l = tid & 63, q = l >> 4, c = l & 15;
  f32x4 acc[2][8];
  const f32x4 zf = {0.f, 0.f, 0.f, 0.f};
  for (int i = 0; i < 2; ++i) for (int j = 0; j < 8; ++j) acc[i][j] = zf;

  for (int kt = 0; kt < DIM / 64; ++kt) {
    __syncthreads();
#pragma unroll
    for (int it = 0; it < 4; ++it) {
      int idx = it * 256 + tid; int r = idx >> 3, ch = idx & 7;
      *(float4*)(sa + r * 72 + ch * 8) = *(const float4*)(A + (size_t)(by * 128 + r) * DIM + kt * 64 + ch * 8);
      *(float4*)(sb + r * 72 + ch * 8) = *(const float4*)(B + (size_t)(bx * 128 + r) * DIM + kt * 64 + ch * 8);
    }
    __syncthreads();
#pragma unroll
    for (int ks = 0; ks < 2; ++ks) {
      f16x8 af[2], bf[8];
#pragma unroll
      for (int tr = 0; tr < 2; ++tr) af[tr] = *(const f16x8*)(sa + (w * 32 + tr * 16 + c) * 72 + ks * 32 + q * 8);
#pragma unroll
      for (int tc = 0; tc < 8; ++tc) bf[tc] = *(const f16x8*)(sb + (tc * 16 + c) * 72 + ks * 32 + q * 8);
#pragma unroll
      for (int tr = 0; tr < 2; ++tr)
#pragma unroll
        for (int tc = 0; tc < 8; ++tc)
          acc[tr][tc] = __builtin_amdgcn_mfma_f32_16x16x32_f16(af[tr], bf[tc], acc[tr][tc], 0, 0, 0);
    }
  }
  // epilogue: scatter into qu(0) ku(1) vu(2) qc(3) kc(4) vcT(5); scale qu,qc by dh^-0.5
#pragma unroll
  for (int tr = 0; tr < 2; ++tr)
#pragma unroll
    for (int tc = 0; tc < 8; ++tc)
#pragma unroll
      for (int r = 0; r < 4; ++r) {
        int row = by * 128 + w * 32 + tr * 16 + q * 4 + r;
        int col = bx * 128 + tc * 16 + c;
        float v = acc[tr][tc][r];
        int t = col >> 10, head = (col >> 6) & 15, dh = col & 63;
        if (t == 0 || t == 3) v *= 0.125f;
        if (t == 5) q6[(size_t)5 * NHSD + (size_t)(head * DH + dh) * SEQ + row] = (f16)v;
        else        q6[(size_t)t * NHSD + (size_t)(head * SEQ + row) * DH + dh] = (f16)v;
      }
}

// ---------------- split-K fused flash: on-the-fly t1/lk tiles + Su + Sc + silu + partial softmax/PV ----------------
// grid 512 = (head, I, split). Each split owns K in [K0,K1) (equal-cost midpoint partition of the
// triangular (K,J) work). Writes UNNORMALIZED partial (m, l, O) for a 128x64 tile; k_merge combines.
// LDS: sa (t1 / P tile, own-wave rows only -> no barrier) + sb (lk tile, cross-wave: 2 barriers/step).
__global__ __launch_bounds__(256, 2) void k_flash(const f16* __restrict__ q6,
                                                  f16* __restrict__ pO, float* __restrict__ pML) {
  __shared__ f16 sa[128 * 128];
  __shared__ f16 sb[128 * 128];
  int bid = blockIdx.x;
  int head = bid >> 5;          // 32 split-blocks per head
  int rsub = bid & 31;
  // decode (I, s) from rsub
  int I = 0, s = 0;
  {
    int acc = 0;
    for (int ii = 0; ii < 16; ++ii) {
      int si = nsplits(ii);
      if (rsub >= acc && rsub < acc + si) { I = ii; s = rsub - acc; }
      acc += si;
    }
  }
  int S_ = nsplits(I);
  int C = (I + 1) * (I + 2) / 2;
  // midpoint equal-cost partition of K in [0,I]: K belongs to seg ((2p+cost)*S_)/(2C)
  int K0 = 16, K1 = 0;
  {
    int p = 0;
    for (int K = 0; K <= I; ++K) {
      int cost = I - K + 1;
      int seg = ((2 * p + cost) * S_) / (2 * C);
      if (seg == s) { if (K < K0) K0 = K; K1 = K + 1; }
      p += cost;
    }
  }

  const f16* qu = q6 + (size_t)0 * NHSD + (size_t)head * SEQ * DH;   // pre-scaled by dh^-0.5
  const f16* ku = q6 + (size_t)1 * NHSD + (size_t)head * SEQ * DH;
  const f16* vu = q6 + (size_t)2 * NHSD + (size_t)head * SEQ * DH;
  const f16* qc = q6 + (size_t)3 * NHSD + (size_t)head * SEQ * DH;   // pre-scaled by dh^-0.5
  const f16* kc = q6 + (size_t)4 * NHSD + (size_t)head * SEQ * DH;
  const f16* vt = q6 + (size_t)5 * NHSD + (size_t)head * DH * SEQ;   // vc transposed [64][2048]
  int tid = threadIdx.x, w = tid >> 6, l = tid & 63, q = l >> 4, c = l & 15;

  f32x4 su[2][8], tacc[2][8], oacc[2][4];
  float m_i[2][4], l_i[2][4];
  const f32x4 zf = {0.f, 0.f, 0.f, 0.f};
  for (int tr = 0; tr < 2; ++tr) for (int tv = 0; tv < 4; ++tv) oacc[tr][tv] = zf;
  for (int tr = 0; tr < 2; ++tr) for (int r = 0; r < 4; ++r) { m_i[tr][r] = -INFINITY; l_i[tr][r] = 0.f; }

  for (int K = K0; K < K1; ++K) {
    for (int tr = 0; tr < 2; ++tr) for (int tc = 0; tc < 8; ++tc) su[tr][tc] = zf;

    for (int J = K; J <= I; ++J) {
      __syncthreads();   // WAR: prior Su-MFMA reads of sb complete before restaging

      // ---- lookahead(K,J) tile: sigmoid(qu_s(K) @ ku(J)^T), keep j>k -> sb (own k-rows) ----
      for (int tr = 0; tr < 2; ++tr) for (int tc = 0; tc < 8; ++tc) tacc[tr][tc] = zf;
#pragma unroll
      for (int ks = 0; ks < 2; ++ks) {
        f16x8 aq[2], bf[8];
#pragma unroll
        for (int tr = 0; tr < 2; ++tr)
          aq[tr] = *(const f16x8*)(qu + (size_t)(K * 128 + w * 32 + tr * 16 + c) * DH + ks * 32 + q * 8);
#pragma unroll
        for (int tc = 0; tc < 8; ++tc)
          bf[tc] = *(const f16x8*)(ku + (size_t)(J * 128 + tc * 16 + c) * DH + ks * 32 + q * 8);
#pragma unroll
        for (int tr = 0; tr < 2; ++tr)
#pragma unroll
          for (int tc = 0; tc < 8; ++tc)
            tacc[tr][tc] = __builtin_amdgcn_mfma_f32_16x16x32_f16(aq[tr], bf[tc], tacc[tr][tc], 0, 0, 0);
      }
#pragma unroll
      for (int tr = 0; tr < 2; ++tr)
#pragma unroll
        for (int tc = 0; tc < 8; ++tc)
#pragma unroll
          for (int r = 0; r < 4; ++r) {
            int row = w * 32 + tr * 16 + q * 4 + r;
            int col = tc * 16 + c;
            int kg = K * 128 + row, jg = J * 128 + col;
            float v = tacc[tr][tc][r];
            f16 ov = (jg > kg) ? (f16)__builtin_amdgcn_rcpf(1.f + __expf(-v)) : (f16)(0.f);
            sb[(row << 7) + (((col >> 3) ^ (row & 15)) << 3) + (col & 7)] = ov;
          }

      // ---- term1(I,J) tile: qc_s(I) @ vu(J)^T, keep j<=i -> sa (own i-rows) ----
      for (int tr = 0; tr < 2; ++tr) for (int tc = 0; tc < 8; ++tc) tacc[tr][tc] = zf;
#pragma unroll
      for (int ks = 0; ks < 2; ++ks) {
        f16x8 aq[2], bf[8];
#pragma unroll
        for (int tr = 0; tr < 2; ++tr)
          aq[tr] = *(const f16x8*)(qc + (size_t)(I * 128 + w * 32 + tr * 16 + c) * DH + ks * 32 + q * 8);
#pragma unroll
        for (int tc = 0; tc < 8; ++tc)
          bf[tc] = *(const f16x8*)(vu + (size_t)(J * 128 + tc * 16 + c) * DH + ks * 32 + q * 8);
#pragma unroll
        for (int tr = 0; tr < 2; ++tr)
#pragma unroll
          for (int tc = 0; tc < 8; ++tc)
            tacc[tr][tc] = __builtin_amdgcn_mfma_f32_16x16x32_f16(aq[tr], bf[tc], tacc[tr][tc], 0, 0, 0);
      }
#pragma unroll
      for (int tr = 0; tr < 2; ++tr)
#pragma unroll
        for (int tc = 0; tc < 8; ++tc)
#pragma unroll
          for (int r = 0; r < 4; ++r) {
            int row = w * 32 + tr * 16 + q * 4 + r;
            int col = tc * 16 + c;
            int ig = I * 128 + row, jg = J * 128 + col;
            float v = tacc[tr][tc][r];
            f16 ov = (jg <= ig) ? (f16)v : (f16)(0.f);
            sa[(row << 7) + (((col >> 3) ^ (row & 15)) << 3) + (col & 7)] = ov;
          }

      __syncthreads();   // RAW: sb (lk tile) visible to all waves

      // ---- Su += t1 @ lk^T over j (128 = 4 chunks of 32) ----
#pragma unroll
      for (int ks = 0; ks < 4; ++ks) {
        int ck = ks * 4 + q;
        f16x8 af[2], bf[8];
#pragma unroll
        for (int tr = 0; tr < 2; ++tr)
          af[tr] = *(const f16x8*)(sa + ((w * 32 + tr * 16 + c) << 7) + ((ck ^ c) << 3));
#pragma unroll
        for (int tc = 0; tc < 8; ++tc)
          bf[tc] = *(const f16x8*)(sb + ((tc * 16 + c) << 7) + ((ck ^ c) << 3));
#pragma unroll
        for (int tr = 0; tr < 2; ++tr)
#pragma unroll
          for (int tc = 0; tc < 8; ++tc)
            su[tr][tc] = __builtin_amdgcn_mfma_f32_16x16x32_f16(af[tr], bf[tc], su[tr][tc], 0, 0, 0);
      }
    }

    // scores = Sc - silu(Su): su = -silu(su), then MFMA adds Sc on top
#pragma unroll
    for (int tr = 0; tr < 2; ++tr)
#pragma unroll
      for (int tc = 0; tc < 8; ++tc)
#pragma unroll
        for (int r = 0; r < 4; ++r) {
          float v = su[tr][tc][r];
          su[tr][tc][r] = -v * __builtin_amdgcn_rcpf(1.f + __expf(-v));
        }
#pragma unroll
    for (int ks = 0; ks < 2; ++ks) {
      f16x8 aq[2], bk[8];
#pragma unroll
      for (int tr = 0; tr < 2; ++tr)
        aq[tr] = *(const f16x8*)(qc + (size_t)(I * 128 + w * 32 + tr * 16 + c) * DH + ks * 32 + q * 8);
#pragma unroll
      for (int tc = 0; tc < 8; ++tc)
        bk[tc] = *(const f16x8*)(kc + (size_t)(K * 128 + tc * 16 + c) * DH + ks * 32 + q * 8);
#pragma unroll
      for (int tr = 0; tr < 2; ++tr)
#pragma unroll
        for (int tc = 0; tc < 8; ++tc)
          su[tr][tc] = __builtin_amdgcn_mfma_f32_16x16x32_f16(aq[tr], bk[tc], su[tr][tc], 0, 0, 0);
    }
    if (K == I) {   // strict causal mask inside the diagonal block
#pragma unroll
      for (int tr = 0; tr < 2; ++tr)
#pragma unroll
        for (int tc = 0; tc < 8; ++tc)
#pragma unroll
          for (int r = 0; r < 4; ++r) {
            int rg = w * 32 + tr * 16 + q * 4 + r;
            int cg = tc * 16 + c;
            if (cg > rg) su[tr][tc][r] = -INFINITY;
          }
    }
    // online softmax (row owned by lanes sharing q; reduce across low-4 lane bits)
#pragma unroll
    for (int tr = 0; tr < 2; ++tr)
#pragma unroll
      for (int r = 0; r < 4; ++r) {
        float mx = su[tr][0][r];
#pragma unroll
        for (int tc = 1; tc < 8; ++tc) mx = fmaxf(mx, su[tr][tc][r]);
        mx = fmaxf(mx, __shfl_xor(mx, 1)); mx = fmaxf(mx, __shfl_xor(mx, 2));
        mx = fmaxf(mx, __shfl_xor(mx, 4)); mx = fmaxf(mx, __shfl_xor(mx, 8));
        float mnew  = fmaxf(m_i[tr][r], mx);
        float alpha = __expf(m_i[tr][r] - mnew);
        float ssum = 0.f;
#pragma unroll
        for (int tc = 0; tc < 8; ++tc) {
          float pp = __expf(su[tr][tc][r] - mnew);
          su[tr][tc][r] = pp;
          ssum += pp;
        }
        ssum += __shfl_xor(ssum, 1); ssum += __shfl_xor(ssum, 2);
        ssum += __shfl_xor(ssum, 4); ssum += __shfl_xor(ssum, 8);
        l_i[tr][r] = l_i[tr][r] * alpha + ssum;
        m_i[tr][r] = mnew;
#pragma unroll
        for (int tv = 0; tv < 4; ++tv) oacc[tr][tv][r] *= alpha;
      }
    // write P into sa (own rows only -> no barrier; other waves never read these rows)
#pragma unroll
    for (int tr = 0; tr < 2; ++tr)
#pragma unroll
      for (int tc = 0; tc < 8; ++tc)
#pragma unroll
        for (int r = 0; r < 4; ++r) {
          int row = w * 32 + tr * 16 + q * 4 + r;
          int col = tc * 16 + c;
          sa[(row << 7) + (((col >> 3) ^ (row & 15)) << 3) + (col & 7)] = (f16)su[tr][tc][r];
        }
    // PV: A = P (own LDS rows), B = vcT straight from global (L2-resident)
#pragma unroll
    for (int ks = 0; ks < 4; ++ks) {
      int ck = ks * 4 + q;
      f16x8 af[2], bv[4];
#pragma unroll
      for (int tr = 0; tr < 2; ++tr)
        af[tr] = *(const f16x8*)(sa + ((w * 32 + tr * 16 + c) << 7) + ((ck ^ c) << 3));
#pragma unroll
      for (int tv = 0; tv < 4; ++tv)
        bv[tv] = *(const f16x8*)(vt + (size_t)(tv * 16 + c) * SEQ + K * 128 + ks * 32 + q * 8);
#pragma unroll
      for (int tr = 0; tr < 2; ++tr)
#pragma unroll
        for (int tv = 0; tv < 4; ++tv)
          oacc[tr][tv] = __builtin_amdgcn_mfma_f32_16x16x32_f16(af[tr], bv[tv], oacc[tr][tv], 0, 0, 0);
    }
  }

  // ---- write unnormalized partial: pO[(h,I,s)][128][64] f16, pML[(h,I,s)][2][128] f32 ----
  int slot = (head * 16 + I) * MAXSPLIT + s;
  f16* po = pO + (size_t)slot * (128 * 64);
  float* pml = pML + (size_t)slot * 256;
  if (c == 0) {
#pragma unroll
    for (int tr = 0; tr < 2; ++tr)
#pragma unroll
      for (int r = 0; r < 4; ++r) {
        int row = w * 32 + tr * 16 + q * 4 + r;
        pml[row] = m_i[tr][r];
        pml[128 + row] = l_i[tr][r];
      }
  }
#pragma unroll
  for (int tr = 0; tr < 2; ++tr)
#pragma unroll
    for (int tv = 0; tv < 4; ++tv)
#pragma unroll
      for (int r = 0; r < 4; ++r) {
        int row = w * 32 + tr * 16 + q * 4 + r;
        int col = tv * 16 + c;
        po[row * 64 + col] = (f16)oacc[tr][tv][r];
      }
}

// ---------------- merge partials -> oh [2048][1024] f16 ----------------
__global__ __launch_bounds__(256) void k_merge(const f16* __restrict__ pO, const float* __restrict__ pML,
                                               f16* __restrict__ oh) {
  int head = blockIdx.x >> 4, I = blockIdx.x & 15;
  int S_ = nsplits(I);
  int tid = threadIdx.x;
  int row = tid >> 1, half = tid & 1;
  int base = (head * 16 + I) * MAXSPLIT;
  float m[MAXSPLIT], lv[MAXSPLIT];
  float mstar = -INFINITY;
#pragma unroll
  for (int s = 0; s < MAXSPLIT; ++s)
    if (s < S_) {
      m[s] = pML[(size_t)(base + s) * 256 + row];
      lv[s] = pML[(size_t)(base + s) * 256 + 128 + row];
      mstar = fmaxf(mstar, m[s]);
    }
  float wt[MAXSPLIT];
  float lsum = 0.f;
#pragma unroll
  for (int s = 0; s < MAXSPLIT; ++s)
    if (s < S_) {
      wt[s] = __expf(m[s] - mstar);
      lsum += lv[s] * wt[s];
    }
  float rinv = __builtin_amdgcn_rcpf(lsum);
#pragma unroll
  for (int cc = 0; cc < 32; cc += 8) {
    float acc[8] = {0.f, 0.f, 0.f, 0.f, 0.f, 0.f, 0.f, 0.f};
#pragma unroll
    for (int s = 0; s < MAXSPLIT; ++s)
      if (s < S_) {
        f16x8 v = *(const f16x8*)(pO + (size_t)(base + s) * 8192 + row * 64 + half * 32 + cc);
#pragma unroll
        for (int e = 0; e < 8; ++e) acc[e] += wt[s] * (float)v[e];
      }
    f16x8 o;
#pragma unroll
    for (int e = 0; e < 8; ++e) o[e] = (f16)(acc[e] * rinv);
    *(f16x8*)(oh + (size_t)(I * 128 + row) * DIM + head * 64 + half * 32 + cc) = o;
  }
}

// ---------------- final GEMM: oh[2048,1024] @ WoT[1024,1024]^T -> fp32 out ----------------
__global__ __launch_bounds__(256) void k_gemm_out(const f16* __restrict__ A, const f16* __restrict__ B,
                                                  float* __restrict__ out) {
  __shared__ f16 sa[128 * 72];
  __shared__ f16 sb[128 * 72];
  int bx = blockIdx.x, by = blockIdx.y;
  int tid = threadIdx.x, w = tid >> 6, l = tid & 63, q = l >> 4, c = l & 15;
  f32x4 acc[2][8];
  const f32x4 zf = {0.f, 0.f, 0.f, 0.f};
  for (int i = 0; i < 2; ++i) for (int j = 0; j < 8; ++j) acc[i][j] = zf;
  for (int kt = 0; kt < DIM / 64; ++kt) {
    __syncthreads();
#pragma unroll
    for (int it = 0; it < 4; ++it) {
      int idx = it * 256 + tid; int r = idx >> 3, ch = idx & 7;
      *(float4*)(sa + r * 72 + ch * 8) = *(const float4*)(A + (size_t)(by * 128 + r) * DIM + kt * 64 + ch * 8);
      *(float4*)(sb + r * 72 + ch * 8) = *(const float4*)(B + (size_t)(bx * 128 + r) * DIM + kt * 64 + ch * 8);
    }
    __syncthreads();
#pragma unroll
    for (int ks = 0; ks < 2; ++ks) {
      f16x8 af[2], bf[8];
#pragma unroll
      for (int tr = 0; tr < 2; ++tr) af[tr] = *(const f16x8*)(sa + (w * 32 + tr * 16 + c) * 72 + ks * 32 + q * 8);
#pragma unroll
      for (int tc = 0; tc < 8; ++tc) bf[tc] = *(const f16x8*)(sb + (tc * 16 + c) * 72 + ks * 32 + q * 8);
#pragma unroll
      for (int tr = 0; tr < 2; ++tr)
#pragma unroll
        for (int tc = 0; tc < 8; ++tc)
          acc[tr][tc] = __builtin_amdgcn_mfma_f32_16x16x32_f16(af[tr], bf[tc], acc[tr][tc], 0, 0, 0);
    }
  }
#pragma unroll
  for (int tr = 0; tr < 2; ++tr)
#pragma unroll
    for (int tc = 0; tc < 8; ++tc)
#pragma unroll
      for (int r = 0; r < 4; ++r) {
        int row = by * 128 + w * 32 + tr * 16 + q * 4 + r;
        int col = bx * 128 + tc * 16 + c;
        out[(size_t)row * DIM + col] = acc[tr][tc][r];
      }
}

extern "C" void kernel_launch(void* const* d_in, const int* in_sizes, int n_in,
                              void* d_out, int out_size, void* d_ws, size_t ws_size,
                              hipStream_t stream) {
  const float* x  = (const float*)d_in[0];
  const float* Wq = (const float*)d_in[1];
  const float* Wo = (const float*)d_in[2];
  float* out = (float*)d_out;

  f16* ws = (f16*)d_ws;
  size_t off = 0;
  f16* q6  = ws + off; off += (size_t)6 * NHSD;                       // 25.2 MB
  f16* xh  = ws + off; off += (size_t)SEQ * DIM;                      // 4 MB
  f16* WqT = ws + off; off += (size_t)NCOLS * DIM;                    // 12.6 MB
  f16* WoT = ws + off; off += (size_t)DIM * DIM;                      // 2 MB
  f16* oh  = ws + off; off += (size_t)SEQ * DIM;                      // 4 MB
  f16* pO  = ws + off; off += (size_t)NH * 16 * MAXSPLIT * 128 * 64;  // 16.8 MB
  float* pML = (float*)(ws + off); off += (size_t)NH * 16 * MAXSPLIT * 256 * 2; // 1 MB
  // total ~66 MB of workspace

  k_cast_x<<<(SEQ * DIM) / 1024, 256, 0, stream>>>(x, xh);
  k_tcast<<<dim3(NCOLS / 64, DIM / 64), 256, 0, stream>>>(Wq, WqT, DIM, NCOLS);
  k_tcast<<<dim3(DIM / 64, DIM / 64), 256, 0, stream>>>(Wo, WoT, DIM, DIM);
  k_gemm_qkv<<<dim3(NCOLS / 128, SEQ / 128), 256, 0, stream>>>(xh, WqT, q6);
  k_flash<<<NH * SPLITS_PER_HEAD, 256, 0, stream>>>(q6, pO, pML);
  k_merge<<<NH * 16, 256, 0, stream>>>(pO, pML, oh);
  k_gemm_out<<<dim3(DIM / 128, SEQ / 128), 256, 0, stream>>>(oh, WoT, out);
}

// Round 4
// 855.503 us; speedup vs baseline: 2.2737x; 2.2737x over previous
//
#include <hip/hip_runtime.h>
#include <math.h>

typedef _Float16 f16;
typedef _Float16 f16x4 __attribute__((ext_vector_type(4)));
typedef _Float16 f16x8 __attribute__((ext_vector_type(8)));
typedef float f32x4 __attribute__((ext_vector_type(4)));

#define SEQ   2048
#define DIM   1024
#define NH    16
#define DH    64
#define NCOLS 6144
#define NHSD  (NH*SEQ*DH)   /* 2,097,152 elements per qkv sub-tensor */
#define MAXSPLIT 4
#define SPLITS_PER_HEAD 32  /* sum of S(I) over I=0..15 */

__device__ __forceinline__ int nsplits(int I) {
  return (I < 7) ? 1 : (I < 11) ? 2 : (I < 14) ? 3 : 4;
}

// ---------------- cast x (fp32 -> f16), vectorized x4 ----------------
__global__ __launch_bounds__(256) void k_cast_x(const float* __restrict__ x, f16* __restrict__ xh) {
  int i = (blockIdx.x * 256 + threadIdx.x) * 4;
  float4 v = *(const float4*)(x + i);
  f16x4 h; h[0] = (f16)v.x; h[1] = (f16)v.y; h[2] = (f16)v.z; h[3] = (f16)v.w;
  *(f16x4*)(xh + i) = h;
}

// ------------- transpose + cast: out[c][r] = (f16) in[r][c], in is R x C -------------
__global__ __launch_bounds__(256) void k_tcast(const float* __restrict__ in, f16* __restrict__ out,
                                               int R, int C) {
  __shared__ f16 t[64 * 66];
  int bc = blockIdx.x, br = blockIdx.y;
  for (int it = 0; it < 16; ++it) {
    int idx = it * 256 + threadIdx.x;
    int r = idx >> 6, c = idx & 63;
    t[r * 66 + c] = (f16)in[(size_t)(br * 64 + r) * C + bc * 64 + c];
  }
  __syncthreads();
  for (int it = 0; it < 16; ++it) {
    int idx = it * 256 + threadIdx.x;
    int oc = idx >> 6, orr = idx & 63;
    out[(size_t)(bc * 64 + oc) * R + br * 64 + orr] = t[orr * 66 + oc];
  }
}

// ---------------- qkv GEMM: xh[2048,1024] @ WqT[6144,1024]^T -> six packed tensors ----------------
__global__ __launch_bounds__(256) void k_gemm_qkv(const f16* __restrict__ A, const f16* __restrict__ B,
                                                  f16* __restrict__ q6) {
  __shared__ f16 sa[128 * 72];
  __shared__ f16 sb[128 * 72];
  int bx = blockIdx.x, by = blockIdx.y;
  int tid = threadIdx.x, w = tid >> 6, l = tid & 63, q = l >> 4, c = l & 15;
  f32x4 acc[2][8];
  const f32x4 zf = {0.f, 0.f, 0.f, 0.f};
  for (int i = 0; i < 2; ++i) for (int j = 0; j < 8; ++j) acc[i][j] = zf;

  for (int kt = 0; kt < DIM / 64; ++kt) {
    __syncthreads();
#pragma unroll
    for (int it = 0; it < 4; ++it) {
      int idx = it * 256 + tid; int r = idx >> 3, ch = idx & 7;
      *(float4*)(sa + r * 72 + ch * 8) = *(const float4*)(A + (size_t)(by * 128 + r) * DIM + kt * 64 + ch * 8);
      *(float4*)(sb + r * 72 + ch * 8) = *(const float4*)(B + (size_t)(bx * 128 + r) * DIM + kt * 64 + ch * 8);
    }
    __syncthreads();
#pragma unroll
    for (int ks = 0; ks < 2; ++ks) {
      f16x8 af[2], bf[8];
#pragma unroll
      for (int tr = 0; tr < 2; ++tr) af[tr] = *(const f16x8*)(sa + (w * 32 + tr * 16 + c) * 72 + ks * 32 + q * 8);
#pragma unroll
      for (int tc = 0; tc < 8; ++tc) bf[tc] = *(const f16x8*)(sb + (tc * 16 + c) * 72 + ks * 32 + q * 8);
#pragma unroll
      for (int tr = 0; tr < 2; ++tr)
#pragma unroll
        for (int tc = 0; tc < 8; ++tc)
          acc[tr][tc] = __builtin_amdgcn_mfma_f32_16x16x32_f16(af[tr], bf[tc], acc[tr][tc], 0, 0, 0);
    }
  }
  // epilogue: scatter into qu(0) ku(1) vu(2) qc(3) kc(4) vcT(5); scale qu,qc by dh^-0.5
#pragma unroll
  for (int tr = 0; tr < 2; ++tr)
#pragma unroll
    for (int tc = 0; tc < 8; ++tc)
#pragma unroll
      for (int r = 0; r < 4; ++r) {
        int row = by * 128 + w * 32 + tr * 16 + q * 4 + r;
        int col = bx * 128 + tc * 16 + c;
        float v = acc[tr][tc][r];
        int t = col >> 10, head = (col >> 6) & 15, dh = col & 63;
        if (t == 0 || t == 3) v *= 0.125f;
        if (t == 5) q6[(size_t)5 * NHSD + (size_t)(head * DH + dh) * SEQ + row] = (f16)v;
        else        q6[(size_t)t * NHSD + (size_t)(head * SEQ + row) * DH + dh] = (f16)v;
      }
}

// ---------------- split-K fused flash: on-the-fly t1/lk tiles + Su + Sc + silu + partial softmax/PV ----------------
// grid 512 = (head, I, split). Each split owns K in [K0,K1). Writes UNNORMALIZED partial (m, l, O);
// k_merge combines. LDS: sa (t1/P, own-wave rows, no barrier) + sb (lk, cross-wave, 2 barriers/step).
// NOTE: launch_bounds(256,1) — NOT (256,2): live state needs ~220 VGPRs; forcing 128 spilled 1.9 GB
// to scratch in R3 (FETCH 1.5 GB). At 256 VGPR the HW still co-schedules 2 blocks/CU (512-block grid).
__global__ __launch_bounds__(256, 1) void k_flash(const f16* __restrict__ q6,
                                                  f16* __restrict__ pO, float* __restrict__ pML) {
  __shared__ f16 sa[128 * 128];
  __shared__ f16 sb[128 * 128];
  int bid = blockIdx.x;
  int head = bid >> 5;          // 32 split-blocks per head
  int rsub = bid & 31;
  // decode (I, s) from rsub
  int I = 0, s = 0;
  {
    int acc = 0;
    for (int ii = 0; ii < 16; ++ii) {
      int si = nsplits(ii);
      if (rsub >= acc && rsub < acc + si) { I = ii; s = rsub - acc; }
      acc += si;
    }
  }
  int S_ = nsplits(I);
  int C = (I + 1) * (I + 2) / 2;
  // midpoint equal-cost partition of K in [0,I]: K belongs to seg ((2p+cost)*S_)/(2C)
  int K0 = 16, K1 = 0;
  {
    int p = 0;
    for (int K = 0; K <= I; ++K) {
      int cost = I - K + 1;
      int seg = ((2 * p + cost) * S_) / (2 * C);
      if (seg == s) { if (K < K0) K0 = K; K1 = K + 1; }
      p += cost;
    }
  }

  const f16* qu = q6 + (size_t)0 * NHSD + (size_t)head * SEQ * DH;   // pre-scaled by dh^-0.5
  const f16* ku = q6 + (size_t)1 * NHSD + (size_t)head * SEQ * DH;
  const f16* vu = q6 + (size_t)2 * NHSD + (size_t)head * SEQ * DH;
  const f16* qc = q6 + (size_t)3 * NHSD + (size_t)head * SEQ * DH;   // pre-scaled by dh^-0.5
  const f16* kc = q6 + (size_t)4 * NHSD + (size_t)head * SEQ * DH;
  const f16* vt = q6 + (size_t)5 * NHSD + (size_t)head * DH * SEQ;   // vc transposed [64][2048]
  int tid = threadIdx.x, w = tid >> 6, l = tid & 63, q = l >> 4, c = l & 15;

  f32x4 su[2][8], tacc[2][8], oacc[2][4];
  float m_i[2][4], l_i[2][4];
  const f32x4 zf = {0.f, 0.f, 0.f, 0.f};
  for (int tr = 0; tr < 2; ++tr) for (int tv = 0; tv < 4; ++tv) oacc[tr][tv] = zf;
  for (int tr = 0; tr < 2; ++tr) for (int r = 0; r < 4; ++r) { m_i[tr][r] = -INFINITY; l_i[tr][r] = 0.f; }

  for (int K = K0; K < K1; ++K) {
    for (int tr = 0; tr < 2; ++tr) for (int tc = 0; tc < 8; ++tc) su[tr][tc] = zf;

    for (int J = K; J <= I; ++J) {
      __syncthreads();   // WAR: prior Su-MFMA reads of sb complete before restaging

      // ---- lookahead(K,J) tile: sigmoid(qu_s(K) @ ku(J)^T), keep j>k -> sb (own k-rows) ----
      for (int tr = 0; tr < 2; ++tr) for (int tc = 0; tc < 8; ++tc) tacc[tr][tc] = zf;
#pragma unroll
      for (int ks = 0; ks < 2; ++ks) {
        f16x8 aq[2], bf[8];
#pragma unroll
        for (int tr = 0; tr < 2; ++tr)
          aq[tr] = *(const f16x8*)(qu + (size_t)(K * 128 + w * 32 + tr * 16 + c) * DH + ks * 32 + q * 8);
#pragma unroll
        for (int tc = 0; tc < 8; ++tc)
          bf[tc] = *(const f16x8*)(ku + (size_t)(J * 128 + tc * 16 + c) * DH + ks * 32 + q * 8);
#pragma unroll
        for (int tr = 0; tr < 2; ++tr)
#pragma unroll
          for (int tc = 0; tc < 8; ++tc)
            tacc[tr][tc] = __builtin_amdgcn_mfma_f32_16x16x32_f16(aq[tr], bf[tc], tacc[tr][tc], 0, 0, 0);
      }
#pragma unroll
      for (int tr = 0; tr < 2; ++tr)
#pragma unroll
        for (int tc = 0; tc < 8; ++tc)
#pragma unroll
          for (int r = 0; r < 4; ++r) {
            int row = w * 32 + tr * 16 + q * 4 + r;
            int col = tc * 16 + c;
            int kg = K * 128 + row, jg = J * 128 + col;
            float v = tacc[tr][tc][r];
            f16 ov = (jg > kg) ? (f16)__builtin_amdgcn_rcpf(1.f + __expf(-v)) : (f16)(0.f);
            sb[(row << 7) + (((col >> 3) ^ (row & 15)) << 3) + (col & 7)] = ov;
          }

      // ---- term1(I,J) tile: qc_s(I) @ vu(J)^T, keep j<=i -> sa (own i-rows) ----
      for (int tr = 0; tr < 2; ++tr) for (int tc = 0; tc < 8; ++tc) tacc[tr][tc] = zf;
#pragma unroll
      for (int ks = 0; ks < 2; ++ks) {
        f16x8 aq[2], bf[8];
#pragma unroll
        for (int tr = 0; tr < 2; ++tr)
          aq[tr] = *(const f16x8*)(qc + (size_t)(I * 128 + w * 32 + tr * 16 + c) * DH + ks * 32 + q * 8);
#pragma unroll
        for (int tc = 0; tc < 8; ++tc)
          bf[tc] = *(const f16x8*)(vu + (size_t)(J * 128 + tc * 16 + c) * DH + ks * 32 + q * 8);
#pragma unroll
        for (int tr = 0; tr < 2; ++tr)
#pragma unroll
          for (int tc = 0; tc < 8; ++tc)
            tacc[tr][tc] = __builtin_amdgcn_mfma_f32_16x16x32_f16(aq[tr], bf[tc], tacc[tr][tc], 0, 0, 0);
      }
#pragma unroll
      for (int tr = 0; tr < 2; ++tr)
#pragma unroll
        for (int tc = 0; tc < 8; ++tc)
#pragma unroll
          for (int r = 0; r < 4; ++r) {
            int row = w * 32 + tr * 16 + q * 4 + r;
            int col = tc * 16 + c;
            int ig = I * 128 + row, jg = J * 128 + col;
            float v = tacc[tr][tc][r];
            f16 ov = (jg <= ig) ? (f16)v : (f16)(0.f);
            sa[(row << 7) + (((col >> 3) ^ (row & 15)) << 3) + (col & 7)] = ov;
          }

      __syncthreads();   // RAW: sb (lk tile) visible to all waves

      // ---- Su += t1 @ lk^T over j (128 = 4 chunks of 32) ----
#pragma unroll
      for (int ks = 0; ks < 4; ++ks) {
        int ck = ks * 4 + q;
        f16x8 af[2], bf[8];
#pragma unroll
        for (int tr = 0; tr < 2; ++tr)
          af[tr] = *(const f16x8*)(sa + ((w * 32 + tr * 16 + c) << 7) + ((ck ^ c) << 3));
#pragma unroll
        for (int tc = 0; tc < 8; ++tc)
          bf[tc] = *(const f16x8*)(sb + ((tc * 16 + c) << 7) + ((ck ^ c) << 3));
#pragma unroll
        for (int tr = 0; tr < 2; ++tr)
#pragma unroll
          for (int tc = 0; tc < 8; ++tc)
            su[tr][tc] = __builtin_amdgcn_mfma_f32_16x16x32_f16(af[tr], bf[tc], su[tr][tc], 0, 0, 0);
      }
    }

    // scores = Sc - silu(Su): su = -silu(su), then MFMA adds Sc on top
#pragma unroll
    for (int tr = 0; tr < 2; ++tr)
#pragma unroll
      for (int tc = 0; tc < 8; ++tc)
#pragma unroll
        for (int r = 0; r < 4; ++r) {
          float v = su[tr][tc][r];
          su[tr][tc][r] = -v * __builtin_amdgcn_rcpf(1.f + __expf(-v));
        }
#pragma unroll
    for (int ks = 0; ks < 2; ++ks) {
      f16x8 aq[2], bk[8];
#pragma unroll
      for (int tr = 0; tr < 2; ++tr)
        aq[tr] = *(const f16x8*)(qc + (size_t)(I * 128 + w * 32 + tr * 16 + c) * DH + ks * 32 + q * 8);
#pragma unroll
      for (int tc = 0; tc < 8; ++tc)
        bk[tc] = *(const f16x8*)(kc + (size_t)(K * 128 + tc * 16 + c) * DH + ks * 32 + q * 8);
#pragma unroll
      for (int tr = 0; tr < 2; ++tr)
#pragma unroll
        for (int tc = 0; tc < 8; ++tc)
          su[tr][tc] = __builtin_amdgcn_mfma_f32_16x16x32_f16(aq[tr], bk[tc], su[tr][tc], 0, 0, 0);
    }
    if (K == I) {   // strict causal mask inside the diagonal block
#pragma unroll
      for (int tr = 0; tr < 2; ++tr)
#pragma unroll
        for (int tc = 0; tc < 8; ++tc)
#pragma unroll
          for (int r = 0; r < 4; ++r) {
            int rg = w * 32 + tr * 16 + q * 4 + r;
            int cg = tc * 16 + c;
            if (cg > rg) su[tr][tc][r] = -INFINITY;
          }
    }
    // online softmax (row owned by lanes sharing q; reduce across low-4 lane bits)
#pragma unroll
    for (int tr = 0; tr < 2; ++tr)
#pragma unroll
      for (int r = 0; r < 4; ++r) {
        float mx = su[tr][0][r];
#pragma unroll
        for (int tc = 1; tc < 8; ++tc) mx = fmaxf(mx, su[tr][tc][r]);
        mx = fmaxf(mx, __shfl_xor(mx, 1)); mx = fmaxf(mx, __shfl_xor(mx, 2));
        mx = fmaxf(mx, __shfl_xor(mx, 4)); mx = fmaxf(mx, __shfl_xor(mx, 8));
        float mnew  = fmaxf(m_i[tr][r], mx);
        float alpha = __expf(m_i[tr][r] - mnew);
        float ssum = 0.f;
#pragma unroll
        for (int tc = 0; tc < 8; ++tc) {
          float pp = __expf(su[tr][tc][r] - mnew);
          su[tr][tc][r] = pp;
          ssum += pp;
        }
        ssum += __shfl_xor(ssum, 1); ssum += __shfl_xor(ssum, 2);
        ssum += __shfl_xor(ssum, 4); ssum += __shfl_xor(ssum, 8);
        l_i[tr][r] = l_i[tr][r] * alpha + ssum;
        m_i[tr][r] = mnew;
#pragma unroll
        for (int tv = 0; tv < 4; ++tv) oacc[tr][tv][r] *= alpha;
      }
    // write P into sa (own rows only -> no barrier; other waves never read these rows)
#pragma unroll
    for (int tr = 0; tr < 2; ++tr)
#pragma unroll
      for (int tc = 0; tc < 8; ++tc)
#pragma unroll
        for (int r = 0; r < 4; ++r) {
          int row = w * 32 + tr * 16 + q * 4 + r;
          int col = tc * 16 + c;
          sa[(row << 7) + (((col >> 3) ^ (row & 15)) << 3) + (col & 7)] = (f16)su[tr][tc][r];
        }
    // PV: A = P (own LDS rows), B = vcT straight from global (L2-resident)
#pragma unroll
    for (int ks = 0; ks < 4; ++ks) {
      int ck = ks * 4 + q;
      f16x8 af[2], bv[4];
#pragma unroll
      for (int tr = 0; tr < 2; ++tr)
        af[tr] = *(const f16x8*)(sa + ((w * 32 + tr * 16 + c) << 7) + ((ck ^ c) << 3));
#pragma unroll
      for (int tv = 0; tv < 4; ++tv)
        bv[tv] = *(const f16x8*)(vt + (size_t)(tv * 16 + c) * SEQ + K * 128 + ks * 32 + q * 8);
#pragma unroll
      for (int tr = 0; tr < 2; ++tr)
#pragma unroll
        for (int tv = 0; tv < 4; ++tv)
          oacc[tr][tv] = __builtin_amdgcn_mfma_f32_16x16x32_f16(af[tr], bv[tv], oacc[tr][tv], 0, 0, 0);
    }
  }

  // ---- write unnormalized partial: pO[(h,I,s)][128][64] f16, pML[(h,I,s)][2][128] f32 ----
  int slot = (head * 16 + I) * MAXSPLIT + s;
  f16* po = pO + (size_t)slot * (128 * 64);
  float* pml = pML + (size_t)slot * 256;
  if (c == 0) {
#pragma unroll
    for (int tr = 0; tr < 2; ++tr)
#pragma unroll
      for (int r = 0; r < 4; ++r) {
        int row = w * 32 + tr * 16 + q * 4 + r;
        pml[row] = m_i[tr][r];
        pml[128 + row] = l_i[tr][r];
      }
  }
#pragma unroll
  for (int tr = 0; tr < 2; ++tr)
#pragma unroll
    for (int tv = 0; tv < 4; ++tv)
#pragma unroll
      for (int r = 0; r < 4; ++r) {
        int row = w * 32 + tr * 16 + q * 4 + r;
        int col = tv * 16 + c;
        po[row * 64 + col] = (f16)oacc[tr][tv][r];
      }
}

// ---------------- merge partials -> oh [2048][1024] f16 ----------------
__global__ __launch_bounds__(256) void k_merge(const f16* __restrict__ pO, const float* __restrict__ pML,
                                               f16* __restrict__ oh) {
  int head = blockIdx.x >> 4, I = blockIdx.x & 15;
  int S_ = nsplits(I);
  int tid = threadIdx.x;
  int row = tid >> 1, half = tid & 1;
  int base = (head * 16 + I) * MAXSPLIT;
  float m[MAXSPLIT], lv[MAXSPLIT];
  float mstar = -INFINITY;
#pragma unroll
  for (int s = 0; s < MAXSPLIT; ++s)
    if (s < S_) {
      m[s] = pML[(size_t)(base + s) * 256 + row];
      lv[s] = pML[(size_t)(base + s) * 256 + 128 + row];
      mstar = fmaxf(mstar, m[s]);
    }
  float wt[MAXSPLIT];
  float lsum = 0.f;
#pragma unroll
  for (int s = 0; s < MAXSPLIT; ++s)
    if (s < S_) {
      wt[s] = __expf(m[s] - mstar);
      lsum += lv[s] * wt[s];
    }
  float rinv = __builtin_amdgcn_rcpf(lsum);
#pragma unroll
  for (int cc = 0; cc < 32; cc += 8) {
    float acc[8] = {0.f, 0.f, 0.f, 0.f, 0.f, 0.f, 0.f, 0.f};
#pragma unroll
    for (int s = 0; s < MAXSPLIT; ++s)
      if (s < S_) {
        f16x8 v = *(const f16x8*)(pO + (size_t)(base + s) * 8192 + row * 64 + half * 32 + cc);
#pragma unroll
        for (int e = 0; e < 8; ++e) acc[e] += wt[s] * (float)v[e];
      }
    f16x8 o;
#pragma unroll
    for (int e = 0; e < 8; ++e) o[e] = (f16)(acc[e] * rinv);
    *(f16x8*)(oh + (size_t)(I * 128 + row) * DIM + head * 64 + half * 32 + cc) = o;
  }
}

// ---------------- final GEMM: oh[2048,1024] @ WoT[1024,1024]^T -> fp32 out ----------------
__global__ __launch_bounds__(256) void k_gemm_out(const f16* __restrict__ A, const f16* __restrict__ B,
                                                  float* __restrict__ out) {
  __shared__ f16 sa[128 * 72];
  __shared__ f16 sb[128 * 72];
  int bx = blockIdx.x, by = blockIdx.y;
  int tid = threadIdx.x, w = tid >> 6, l = tid & 63, q = l >> 4, c = l & 15;
  f32x4 acc[2][8];
  const f32x4 zf = {0.f, 0.f, 0.f, 0.f};
  for (int i = 0; i < 2; ++i) for (int j = 0; j < 8; ++j) acc[i][j] = zf;
  for (int kt = 0; kt < DIM / 64; ++kt) {
    __syncthreads();
#pragma unroll
    for (int it = 0; it < 4; ++it) {
      int idx = it * 256 + tid; int r = idx >> 3, ch = idx & 7;
      *(float4*)(sa + r * 72 + ch * 8) = *(const float4*)(A + (size_t)(by * 128 + r) * DIM + kt * 64 + ch * 8);
      *(float4*)(sb + r * 72 + ch * 8) = *(const float4*)(B + (size_t)(bx * 128 + r) * DIM + kt * 64 + ch * 8);
    }
    __syncthreads();
#pragma unroll
    for (int ks = 0; ks < 2; ++ks) {
      f16x8 af[2], bf[8];
#pragma unroll
      for (int tr = 0; tr < 2; ++tr) af[tr] = *(const f16x8*)(sa + (w * 32 + tr * 16 + c) * 72 + ks * 32 + q * 8);
#pragma unroll
      for (int tc = 0; tc < 8; ++tc) bf[tc] = *(const f16x8*)(sb + (tc * 16 + c) * 72 + ks * 32 + q * 8);
#pragma unroll
      for (int tr = 0; tr < 2; ++tr)
#pragma unroll
        for (int tc = 0; tc < 8; ++tc)
          acc[tr][tc] = __builtin_amdgcn_mfma_f32_16x16x32_f16(af[tr], bf[tc], acc[tr][tc], 0, 0, 0);
    }
  }
#pragma unroll
  for (int tr = 0; tr < 2; ++tr)
#pragma unroll
    for (int tc = 0; tc < 8; ++tc)
#pragma unroll
      for (int r = 0; r < 4; ++r) {
        int row = by * 128 + w * 32 + tr * 16 + q * 4 + r;
        int col = bx * 128 + tc * 16 + c;
        out[(size_t)row * DIM + col] = acc[tr][tc][r];
      }
}

extern "C" void kernel_launch(void* const* d_in, const int* in_sizes, int n_in,
                              void* d_out, int out_size, void* d_ws, size_t ws_size,
                              hipStream_t stream) {
  const float* x  = (const float*)d_in[0];
  const float* Wq = (const float*)d_in[1];
  const float* Wo = (const float*)d_in[2];
  float* out = (float*)d_out;

  f16* ws = (f16*)d_ws;
  size_t off = 0;
  f16* q6  = ws + off; off += (size_t)6 * NHSD;                       // 25.2 MB
  f16* xh  = ws + off; off += (size_t)SEQ * DIM;                      // 4 MB
  f16* WqT = ws + off; off += (size_t)NCOLS * DIM;                    // 12.6 MB
  f16* WoT = ws + off; off += (size_t)DIM * DIM;                      // 2 MB
  f16* oh  = ws + off; off += (size_t)SEQ * DIM;                      // 4 MB
  f16* pO  = ws + off; off += (size_t)NH * 16 * MAXSPLIT * 128 * 64;  // 16.8 MB
  float* pML = (float*)(ws + off); off += (size_t)NH * 16 * MAXSPLIT * 256 * 2; // 1 MB
  // total ~66 MB of workspace

  k_cast_x<<<(SEQ * DIM) / 1024, 256, 0, stream>>>(x, xh);
  k_tcast<<<dim3(NCOLS / 64, DIM / 64), 256, 0, stream>>>(Wq, WqT, DIM, NCOLS);
  k_tcast<<<dim3(DIM / 64, DIM / 64), 256, 0, stream>>>(Wo, WoT, DIM, DIM);
  k_gemm_qkv<<<dim3(NCOLS / 128, SEQ / 128), 256, 0, stream>>>(xh, WqT, q6);
  k_flash<<<NH * SPLITS_PER_HEAD, 256, 0, stream>>>(q6, pO, pML);
  k_merge<<<NH * 16, 256, 0, stream>>>(pO, pML, oh);
  k_gemm_out<<<dim3(DIM / 128, SEQ / 128), 256, 0, stream>>>(oh, WoT, out);
}

// Round 5
// 773.688 us; speedup vs baseline: 2.5142x; 1.1057x over previous
//
#include <hip/hip_runtime.h>
#include <math.h>

typedef _Float16 f16;
typedef _Float16 f16x4 __attribute__((ext_vector_type(4)));
typedef _Float16 f16x8 __attribute__((ext_vector_type(8)));
typedef float f32x4 __attribute__((ext_vector_type(4)));

#define SEQ   2048
#define DIM   1024
#define NH    16
#define DH    64
#define NCOLS 6144
#define NHSD  (NH*SEQ*DH)   /* 2,097,152 elements per qkv sub-tensor */
#define MAXSPLIT 4
#define SPLITS_PER_HEAD 32  /* sum of S(I) over I=0..15 */

__device__ __forceinline__ int nsplits(int I) {
  return (I < 7) ? 1 : (I < 11) ? 2 : (I < 14) ? 3 : 4;
}

// ---------------- cast x (fp32 -> f16), vectorized x4 ----------------
__global__ __launch_bounds__(256) void k_cast_x(const float* __restrict__ x, f16* __restrict__ xh) {
  int i = (blockIdx.x * 256 + threadIdx.x) * 4;
  float4 v = *(const float4*)(x + i);
  f16x4 h; h[0] = (f16)v.x; h[1] = (f16)v.y; h[2] = (f16)v.z; h[3] = (f16)v.w;
  *(f16x4*)(xh + i) = h;
}

// ------------- transpose + cast: out[c][r] = (f16) in[r][c], in is R x C -------------
__global__ __launch_bounds__(256) void k_tcast(const float* __restrict__ in, f16* __restrict__ out,
                                               int R, int C) {
  __shared__ f16 t[64 * 66];
  int bc = blockIdx.x, br = blockIdx.y;
  for (int it = 0; it < 16; ++it) {
    int idx = it * 256 + threadIdx.x;
    int r = idx >> 6, c = idx & 63;
    t[r * 66 + c] = (f16)in[(size_t)(br * 64 + r) * C + bc * 64 + c];
  }
  __syncthreads();
  for (int it = 0; it < 16; ++it) {
    int idx = it * 256 + threadIdx.x;
    int oc = idx >> 6, orr = idx & 63;
    out[(size_t)(bc * 64 + oc) * R + br * 64 + orr] = t[orr * 66 + oc];
  }
}

// ---------------- qkv GEMM: xh[2048,1024] @ WqT[6144,1024]^T -> six packed tensors ----------------
__global__ __launch_bounds__(256) void k_gemm_qkv(const f16* __restrict__ A, const f16* __restrict__ B,
                                                  f16* __restrict__ q6) {
  __shared__ f16 sa[128 * 72];
  __shared__ f16 sb[128 * 72];
  int bx = blockIdx.x, by = blockIdx.y;
  int tid = threadIdx.x, w = tid >> 6, l = tid & 63, q = l >> 4, c = l & 15;
  f32x4 acc[2][8];
  const f32x4 zf = {0.f, 0.f, 0.f, 0.f};
  for (int i = 0; i < 2; ++i) for (int j = 0; j < 8; ++j) acc[i][j] = zf;

  for (int kt = 0; kt < DIM / 64; ++kt) {
    __syncthreads();
#pragma unroll
    for (int it = 0; it < 4; ++it) {
      int idx = it * 256 + tid; int r = idx >> 3, ch = idx & 7;
      *(float4*)(sa + r * 72 + ch * 8) = *(const float4*)(A + (size_t)(by * 128 + r) * DIM + kt * 64 + ch * 8);
      *(float4*)(sb + r * 72 + ch * 8) = *(const float4*)(B + (size_t)(bx * 128 + r) * DIM + kt * 64 + ch * 8);
    }
    __syncthreads();
#pragma unroll
    for (int ks = 0; ks < 2; ++ks) {
      f16x8 af[2], bf[8];
#pragma unroll
      for (int tr = 0; tr < 2; ++tr) af[tr] = *(const f16x8*)(sa + (w * 32 + tr * 16 + c) * 72 + ks * 32 + q * 8);
#pragma unroll
      for (int tc = 0; tc < 8; ++tc) bf[tc] = *(const f16x8*)(sb + (tc * 16 + c) * 72 + ks * 32 + q * 8);
#pragma unroll
      for (int tr = 0; tr < 2; ++tr)
#pragma unroll
        for (int tc = 0; tc < 8; ++tc)
          acc[tr][tc] = __builtin_amdgcn_mfma_f32_16x16x32_f16(af[tr], bf[tc], acc[tr][tc], 0, 0, 0);
    }
  }
  // epilogue: scatter into qu(0) ku(1) vu(2) qc(3) kc(4) vcT(5); scale qu,qc by dh^-0.5
#pragma unroll
  for (int tr = 0; tr < 2; ++tr)
#pragma unroll
    for (int tc = 0; tc < 8; ++tc)
#pragma unroll
      for (int r = 0; r < 4; ++r) {
        int row = by * 128 + w * 32 + tr * 16 + q * 4 + r;
        int col = bx * 128 + tc * 16 + c;
        float v = acc[tr][tc][r];
        int t = col >> 10, head = (col >> 6) & 15, dh = col & 63;
        if (t == 0 || t == 3) v *= 0.125f;
        if (t == 5) q6[(size_t)5 * NHSD + (size_t)(head * DH + dh) * SEQ + row] = (f16)v;
        else        q6[(size_t)t * NHSD + (size_t)(head * SEQ + row) * DH + dh] = (f16)v;
      }
}

// ---------------- split-K fused flash: on-the-fly t1/lk tiles + Su + Sc + silu + partial softmax/PV ----------------
// grid 512 = (head, I, split). Each split owns K in [K0,K1). Writes UNNORMALIZED partial (m, l, O);
// k_merge combines. LDS: sa (t1/P, own-wave rows, no barrier) + sb (lk, cross-wave, 2 barriers/step).
// launch_bounds(256,1): live state ~220 VGPR; forcing (256,2) spilled 1.9 GB in R3.
// XCD SWIZZLE (R5): head = ((bid&7)<<1)|((bid>>3)&1) so each XCD (bid%8 under round-robin dispatch)
// hosts exactly 2 heads -> 3 MB working set < 4 MB per-XCD L2. R4's head=bid>>5 spread every head
// across all 8 XCDs: FETCH 153 MB ~= 16 heads x 1.5 MB x 8 XCDs, and every frag load paid HBM latency.
__global__ __launch_bounds__(256, 1) void k_flash(const f16* __restrict__ q6,
                                                  f16* __restrict__ pO, float* __restrict__ pML) {
  __shared__ f16 sa[128 * 128];
  __shared__ f16 sb[128 * 128];
  int bid = blockIdx.x;
  int head = ((bid & 7) << 1) | ((bid >> 3) & 1);
  int rsub = bid >> 4;          // [0,32): split-block index within head
  // decode (I, s) from rsub
  int I = 0, s = 0;
  {
    int acc = 0;
    for (int ii = 0; ii < 16; ++ii) {
      int si = nsplits(ii);
      if (rsub >= acc && rsub < acc + si) { I = ii; s = rsub - acc; }
      acc += si;
    }
  }
  int S_ = nsplits(I);
  int C = (I + 1) * (I + 2) / 2;
  // midpoint equal-cost partition of K in [0,I]: K belongs to seg ((2p+cost)*S_)/(2C)
  int K0 = 16, K1 = 0;
  {
    int p = 0;
    for (int K = 0; K <= I; ++K) {
      int cost = I - K + 1;
      int seg = ((2 * p + cost) * S_) / (2 * C);
      if (seg == s) { if (K < K0) K0 = K; K1 = K + 1; }
      p += cost;
    }
  }

  const f16* qu = q6 + (size_t)0 * NHSD + (size_t)head * SEQ * DH;   // pre-scaled by dh^-0.5
  const f16* ku = q6 + (size_t)1 * NHSD + (size_t)head * SEQ * DH;
  const f16* vu = q6 + (size_t)2 * NHSD + (size_t)head * SEQ * DH;
  const f16* qc = q6 + (size_t)3 * NHSD + (size_t)head * SEQ * DH;   // pre-scaled by dh^-0.5
  const f16* kc = q6 + (size_t)4 * NHSD + (size_t)head * SEQ * DH;
  const f16* vt = q6 + (size_t)5 * NHSD + (size_t)head * DH * SEQ;   // vc transposed [64][2048]
  int tid = threadIdx.x, w = tid >> 6, l = tid & 63, q = l >> 4, c = l & 15;

  f32x4 su[2][8], tacc[2][8], oacc[2][4];
  float m_i[2][4], l_i[2][4];
  const f32x4 zf = {0.f, 0.f, 0.f, 0.f};
  for (int tr = 0; tr < 2; ++tr) for (int tv = 0; tv < 4; ++tv) oacc[tr][tv] = zf;
  for (int tr = 0; tr < 2; ++tr) for (int r = 0; r < 4; ++r) { m_i[tr][r] = -INFINITY; l_i[tr][r] = 0.f; }

  for (int K = K0; K < K1; ++K) {
    for (int tr = 0; tr < 2; ++tr) for (int tc = 0; tc < 8; ++tc) su[tr][tc] = zf;

    for (int J = K; J <= I; ++J) {
      __syncthreads();   // WAR: prior Su-MFMA reads of sb complete before restaging

      // ---- lookahead(K,J) tile: sigmoid(qu_s(K) @ ku(J)^T), keep j>k -> sb (own k-rows) ----
      for (int tr = 0; tr < 2; ++tr) for (int tc = 0; tc < 8; ++tc) tacc[tr][tc] = zf;
#pragma unroll
      for (int ks = 0; ks < 2; ++ks) {
        f16x8 aq[2], bf[8];
#pragma unroll
        for (int tr = 0; tr < 2; ++tr)
          aq[tr] = *(const f16x8*)(qu + (size_t)(K * 128 + w * 32 + tr * 16 + c) * DH + ks * 32 + q * 8);
#pragma unroll
        for (int tc = 0; tc < 8; ++tc)
          bf[tc] = *(const f16x8*)(ku + (size_t)(J * 128 + tc * 16 + c) * DH + ks * 32 + q * 8);
#pragma unroll
        for (int tr = 0; tr < 2; ++tr)
#pragma unroll
          for (int tc = 0; tc < 8; ++tc)
            tacc[tr][tc] = __builtin_amdgcn_mfma_f32_16x16x32_f16(aq[tr], bf[tc], tacc[tr][tc], 0, 0, 0);
      }
#pragma unroll
      for (int tr = 0; tr < 2; ++tr)
#pragma unroll
        for (int tc = 0; tc < 8; ++tc)
#pragma unroll
          for (int r = 0; r < 4; ++r) {
            int row = w * 32 + tr * 16 + q * 4 + r;
            int col = tc * 16 + c;
            int kg = K * 128 + row, jg = J * 128 + col;
            float v = tacc[tr][tc][r];
            f16 ov = (jg > kg) ? (f16)__builtin_amdgcn_rcpf(1.f + __expf(-v)) : (f16)(0.f);
            sb[(row << 7) + (((col >> 3) ^ (row & 15)) << 3) + (col & 7)] = ov;
          }

      // ---- term1(I,J) tile: qc_s(I) @ vu(J)^T, keep j<=i -> sa (own i-rows) ----
      for (int tr = 0; tr < 2; ++tr) for (int tc = 0; tc < 8; ++tc) tacc[tr][tc] = zf;
#pragma unroll
      for (int ks = 0; ks < 2; ++ks) {
        f16x8 aq[2], bf[8];
#pragma unroll
        for (int tr = 0; tr < 2; ++tr)
          aq[tr] = *(const f16x8*)(qc + (size_t)(I * 128 + w * 32 + tr * 16 + c) * DH + ks * 32 + q * 8);
#pragma unroll
        for (int tc = 0; tc < 8; ++tc)
          bf[tc] = *(const f16x8*)(vu + (size_t)(J * 128 + tc * 16 + c) * DH + ks * 32 + q * 8);
#pragma unroll
        for (int tr = 0; tr < 2; ++tr)
#pragma unroll
          for (int tc = 0; tc < 8; ++tc)
            tacc[tr][tc] = __builtin_amdgcn_mfma_f32_16x16x32_f16(aq[tr], bf[tc], tacc[tr][tc], 0, 0, 0);
      }
#pragma unroll
      for (int tr = 0; tr < 2; ++tr)
#pragma unroll
        for (int tc = 0; tc < 8; ++tc)
#pragma unroll
          for (int r = 0; r < 4; ++r) {
            int row = w * 32 + tr * 16 + q * 4 + r;
            int col = tc * 16 + c;
            int ig = I * 128 + row, jg = J * 128 + col;
            float v = tacc[tr][tc][r];
            f16 ov = (jg <= ig) ? (f16)v : (f16)(0.f);
            sa[(row << 7) + (((col >> 3) ^ (row & 15)) << 3) + (col & 7)] = ov;
          }

      __syncthreads();   // RAW: sb (lk tile) visible to all waves

      // ---- Su += t1 @ lk^T over j (128 = 4 chunks of 32) ----
#pragma unroll
      for (int ks = 0; ks < 4; ++ks) {
        int ck = ks * 4 + q;
        f16x8 af[2], bf[8];
#pragma unroll
        for (int tr = 0; tr < 2; ++tr)
          af[tr] = *(const f16x8*)(sa + ((w * 32 + tr * 16 + c) << 7) + ((ck ^ c) << 3));
#pragma unroll
        for (int tc = 0; tc < 8; ++tc)
          bf[tc] = *(const f16x8*)(sb + ((tc * 16 + c) << 7) + ((ck ^ c) << 3));
#pragma unroll
        for (int tr = 0; tr < 2; ++tr)
#pragma unroll
          for (int tc = 0; tc < 8; ++tc)
            su[tr][tc] = __builtin_amdgcn_mfma_f32_16x16x32_f16(af[tr], bf[tc], su[tr][tc], 0, 0, 0);
      }
    }

    // scores = Sc - silu(Su): su = -silu(su), then MFMA adds Sc on top
#pragma unroll
    for (int tr = 0; tr < 2; ++tr)
#pragma unroll
      for (int tc = 0; tc < 8; ++tc)
#pragma unroll
        for (int r = 0; r < 4; ++r) {
          float v = su[tr][tc][r];
          su[tr][tc][r] = -v * __builtin_amdgcn_rcpf(1.f + __expf(-v));
        }
#pragma unroll
    for (int ks = 0; ks < 2; ++ks) {
      f16x8 aq[2], bk[8];
#pragma unroll
      for (int tr = 0; tr < 2; ++tr)
        aq[tr] = *(const f16x8*)(qc + (size_t)(I * 128 + w * 32 + tr * 16 + c) * DH + ks * 32 + q * 8);
#pragma unroll
      for (int tc = 0; tc < 8; ++tc)
        bk[tc] = *(const f16x8*)(kc + (size_t)(K * 128 + tc * 16 + c) * DH + ks * 32 + q * 8);
#pragma unroll
      for (int tr = 0; tr < 2; ++tr)
#pragma unroll
        for (int tc = 0; tc < 8; ++tc)
          su[tr][tc] = __builtin_amdgcn_mfma_f32_16x16x32_f16(aq[tr], bk[tc], su[tr][tc], 0, 0, 0);
    }
    if (K == I) {   // strict causal mask inside the diagonal block
#pragma unroll
      for (int tr = 0; tr < 2; ++tr)
#pragma unroll
        for (int tc = 0; tc < 8; ++tc)
#pragma unroll
          for (int r = 0; r < 4; ++r) {
            int rg = w * 32 + tr * 16 + q * 4 + r;
            int cg = tc * 16 + c;
            if (cg > rg) su[tr][tc][r] = -INFINITY;
          }
    }
    // online softmax (row owned by lanes sharing q; reduce across low-4 lane bits)
#pragma unroll
    for (int tr = 0; tr < 2; ++tr)
#pragma unroll
      for (int r = 0; r < 4; ++r) {
        float mx = su[tr][0][r];
#pragma unroll
        for (int tc = 1; tc < 8; ++tc) mx = fmaxf(mx, su[tr][tc][r]);
        mx = fmaxf(mx, __shfl_xor(mx, 1)); mx = fmaxf(mx, __shfl_xor(mx, 2));
        mx = fmaxf(mx, __shfl_xor(mx, 4)); mx = fmaxf(mx, __shfl_xor(mx, 8));
        float mnew  = fmaxf(m_i[tr][r], mx);
        float alpha = __expf(m_i[tr][r] - mnew);
        float ssum = 0.f;
#pragma unroll
        for (int tc = 0; tc < 8; ++tc) {
          float pp = __expf(su[tr][tc][r] - mnew);
          su[tr][tc][r] = pp;
          ssum += pp;
        }
        ssum += __shfl_xor(ssum, 1); ssum += __shfl_xor(ssum, 2);
        ssum += __shfl_xor(ssum, 4); ssum += __shfl_xor(ssum, 8);
        l_i[tr][r] = l_i[tr][r] * alpha + ssum;
        m_i[tr][r] = mnew;
#pragma unroll
        for (int tv = 0; tv < 4; ++tv) oacc[tr][tv][r] *= alpha;
      }
    // write P into sa (own rows only -> no barrier; other waves never read these rows)
#pragma unroll
    for (int tr = 0; tr < 2; ++tr)
#pragma unroll
      for (int tc = 0; tc < 8; ++tc)
#pragma unroll
        for (int r = 0; r < 4; ++r) {
          int row = w * 32 + tr * 16 + q * 4 + r;
          int col = tc * 16 + c;
          sa[(row << 7) + (((col >> 3) ^ (row & 15)) << 3) + (col & 7)] = (f16)su[tr][tc][r];
        }
    // PV: A = P (own LDS rows), B = vcT straight from global (L2-resident)
#pragma unroll
    for (int ks = 0; ks < 4; ++ks) {
      int ck = ks * 4 + q;
      f16x8 af[2], bv[4];
#pragma unroll
      for (int tr = 0; tr < 2; ++tr)
        af[tr] = *(const f16x8*)(sa + ((w * 32 + tr * 16 + c) << 7) + ((ck ^ c) << 3));
#pragma unroll
      for (int tv = 0; tv < 4; ++tv)
        bv[tv] = *(const f16x8*)(vt + (size_t)(tv * 16 + c) * SEQ + K * 128 + ks * 32 + q * 8);
#pragma unroll
      for (int tr = 0; tr < 2; ++tr)
#pragma unroll
        for (int tv = 0; tv < 4; ++tv)
          oacc[tr][tv] = __builtin_amdgcn_mfma_f32_16x16x32_f16(af[tr], bv[tv], oacc[tr][tv], 0, 0, 0);
    }
  }

  // ---- write unnormalized partial: pO[(h,I,s)][128][64] f16, pML[(h,I,s)][2][128] f32 ----
  int slot = (head * 16 + I) * MAXSPLIT + s;
  f16* po = pO + (size_t)slot * (128 * 64);
  float* pml = pML + (size_t)slot * 256;
  if (c == 0) {
#pragma unroll
    for (int tr = 0; tr < 2; ++tr)
#pragma unroll
      for (int r = 0; r < 4; ++r) {
        int row = w * 32 + tr * 16 + q * 4 + r;
        pml[row] = m_i[tr][r];
        pml[128 + row] = l_i[tr][r];
      }
  }
#pragma unroll
  for (int tr = 0; tr < 2; ++tr)
#pragma unroll
    for (int tv = 0; tv < 4; ++tv)
#pragma unroll
      for (int r = 0; r < 4; ++r) {
        int row = w * 32 + tr * 16 + q * 4 + r;
        int col = tv * 16 + c;
        po[row * 64 + col] = (f16)oacc[tr][tv][r];
      }
}

// ---------------- merge partials -> oh [2048][1024] f16 ----------------
__global__ __launch_bounds__(256) void k_merge(const f16* __restrict__ pO, const float* __restrict__ pML,
                                               f16* __restrict__ oh) {
  int head = blockIdx.x >> 4, I = blockIdx.x & 15;
  int S_ = nsplits(I);
  int tid = threadIdx.x;
  int row = tid >> 1, half = tid & 1;
  int base = (head * 16 + I) * MAXSPLIT;
  float m[MAXSPLIT], lv[MAXSPLIT];
  float mstar = -INFINITY;
#pragma unroll
  for (int s = 0; s < MAXSPLIT; ++s)
    if (s < S_) {
      m[s] = pML[(size_t)(base + s) * 256 + row];
      lv[s] = pML[(size_t)(base + s) * 256 + 128 + row];
      mstar = fmaxf(mstar, m[s]);
    }
  float wt[MAXSPLIT];
  float lsum = 0.f;
#pragma unroll
  for (int s = 0; s < MAXSPLIT; ++s)
    if (s < S_) {
      wt[s] = __expf(m[s] - mstar);
      lsum += lv[s] * wt[s];
    }
  float rinv = __builtin_amdgcn_rcpf(lsum);
#pragma unroll
  for (int cc = 0; cc < 32; cc += 8) {
    float acc[8] = {0.f, 0.f, 0.f, 0.f, 0.f, 0.f, 0.f, 0.f};
#pragma unroll
    for (int s = 0; s < MAXSPLIT; ++s)
      if (s < S_) {
        f16x8 v = *(const f16x8*)(pO + (size_t)(base + s) * 8192 + row * 64 + half * 32 + cc);
#pragma unroll
        for (int e = 0; e < 8; ++e) acc[e] += wt[s] * (float)v[e];
      }
    f16x8 o;
#pragma unroll
    for (int e = 0; e < 8; ++e) o[e] = (f16)(acc[e] * rinv);
    *(f16x8*)(oh + (size_t)(I * 128 + row) * DIM + head * 64 + half * 32 + cc) = o;
  }
}

// ---------------- final GEMM: oh[2048,1024] @ WoT[1024,1024]^T -> fp32 out ----------------
__global__ __launch_bounds__(256) void k_gemm_out(const f16* __restrict__ A, const f16* __restrict__ B,
                                                  float* __restrict__ out) {
  __shared__ f16 sa[128 * 72];
  __shared__ f16 sb[128 * 72];
  int bx = blockIdx.x, by = blockIdx.y;
  int tid = threadIdx.x, w = tid >> 6, l = tid & 63, q = l >> 4, c = l & 15;
  f32x4 acc[2][8];
  const f32x4 zf = {0.f, 0.f, 0.f, 0.f};
  for (int i = 0; i < 2; ++i) for (int j = 0; j < 8; ++j) acc[i][j] = zf;
  for (int kt = 0; kt < DIM / 64; ++kt) {
    __syncthreads();
#pragma unroll
    for (int it = 0; it < 4; ++it) {
      int idx = it * 256 + tid; int r = idx >> 3, ch = idx & 7;
      *(float4*)(sa + r * 72 + ch * 8) = *(const float4*)(A + (size_t)(by * 128 + r) * DIM + kt * 64 + ch * 8);
      *(float4*)(sb + r * 72 + ch * 8) = *(const float4*)(B + (size_t)(bx * 128 + r) * DIM + kt * 64 + ch * 8);
    }
    __syncthreads();
#pragma unroll
    for (int ks = 0; ks < 2; ++ks) {
      f16x8 af[2], bf[8];
#pragma unroll
      for (int tr = 0; tr < 2; ++tr) af[tr] = *(const f16x8*)(sa + (w * 32 + tr * 16 + c) * 72 + ks * 32 + q * 8);
#pragma unroll
      for (int tc = 0; tc < 8; ++tc) bf[tc] = *(const f16x8*)(sb + (tc * 16 + c) * 72 + ks * 32 + q * 8);
#pragma unroll
      for (int tr = 0; tr < 2; ++tr)
#pragma unroll
        for (int tc = 0; tc < 8; ++tc)
          acc[tr][tc] = __builtin_amdgcn_mfma_f32_16x16x32_f16(af[tr], bf[tc], acc[tr][tc], 0, 0, 0);
    }
  }
#pragma unroll
  for (int tr = 0; tr < 2; ++tr)
#pragma unroll
    for (int tc = 0; tc < 8; ++tc)
#pragma unroll
      for (int r = 0; r < 4; ++r) {
        int row = by * 128 + w * 32 + tr * 16 + q * 4 + r;
        int col = bx * 128 + tc * 16 + c;
        out[(size_t)row * DIM + col] = acc[tr][tc][r];
      }
}

extern "C" void kernel_launch(void* const* d_in, const int* in_sizes, int n_in,
                              void* d_out, int out_size, void* d_ws, size_t ws_size,
                              hipStream_t stream) {
  const float* x  = (const float*)d_in[0];
  const float* Wq = (const float*)d_in[1];
  const float* Wo = (const float*)d_in[2];
  float* out = (float*)d_out;

  f16* ws = (f16*)d_ws;
  size_t off = 0;
  f16* q6  = ws + off; off += (size_t)6 * NHSD;                       // 25.2 MB
  f16* xh  = ws + off; off += (size_t)SEQ * DIM;                      // 4 MB
  f16* WqT = ws + off; off += (size_t)NCOLS * DIM;                    // 12.6 MB
  f16* WoT = ws + off; off += (size_t)DIM * DIM;                      // 2 MB
  f16* oh  = ws + off; off += (size_t)SEQ * DIM;                      // 4 MB
  f16* pO  = ws + off; off += (size_t)NH * 16 * MAXSPLIT * 128 * 64;  // 16.8 MB
  float* pML = (float*)(ws + off); off += (size_t)NH * 16 * MAXSPLIT * 256 * 2; // 1 MB
  // total ~66 MB of workspace

  k_cast_x<<<(SEQ * DIM) / 1024, 256, 0, stream>>>(x, xh);
  k_tcast<<<dim3(NCOLS / 64, DIM / 64), 256, 0, stream>>>(Wq, WqT, DIM, NCOLS);
  k_tcast<<<dim3(DIM / 64, DIM / 64), 256, 0, stream>>>(Wo, WoT, DIM, DIM);
  k_gemm_qkv<<<dim3(NCOLS / 128, SEQ / 128), 256, 0, stream>>>(xh, WqT, q6);
  k_flash<<<NH * SPLITS_PER_HEAD, 256, 0, stream>>>(q6, pO, pML);
  k_merge<<<NH * 16, 256, 0, stream>>>(pO, pML, oh);
  k_gemm_out<<<dim3(DIM / 128, SEQ / 128), 256, 0, stream>>>(oh, WoT, out);
}